// Round 1
// baseline (1819.040 us; speedup 1.0000x reference)
//
#include <hip/hip_runtime.h>
#include <math.h>

#define BB 64
#define LL 384
#define DD 128
#define HH 8
#define DHH 16
#define DEPTH 6
#define FFD 512
#define MROWS (BB*LL)      // 24576
#define COUT 128
#define KP (LL*DD)         // 49152

// ---------------- embed + axial pos ----------------
__global__ __launch_bounds__(256) void embed_kernel(
    const int* __restrict__ x_enc, const float* __restrict__ emb,
    const float* __restrict__ pos1, const float* __restrict__ pos2,
    float* __restrict__ x1, float* __restrict__ x2)
{
    int t = blockIdx.x * 256 + threadIdx.x;      // over MROWS * 32 float4
    int row = t >> 5;
    int c4 = t & 31;
    int l = row % LL;
    int tok = x_enc[row];
    float4 a = ((const float4*)(emb + (size_t)tok * DD))[c4];
    float4 b = ((const float4*)(pos1 + (l / 25) * DD))[c4];
    float4 c = ((const float4*)(pos2 + (l % 25) * DD))[c4];
    float4 r = make_float4(a.x + b.x + c.x, a.y + b.y + c.y,
                           a.z + b.z + c.z, a.w + b.w + c.w);
    ((float4*)x1)[t] = r;
    ((float4*)x2)[t] = r;
}

// ---------------- LayerNorm (wave per row, 4 rows/block) ----------------
__device__ __forceinline__ void ln_row(float2 v, float g0, float g1, float b0, float b1,
                                       float* yp, int lane)
{
    float s = v.x + v.y;
    float sq = v.x * v.x + v.y * v.y;
    #pragma unroll
    for (int off = 32; off > 0; off >>= 1) {
        s += __shfl_down(s, off, 64);
        sq += __shfl_down(sq, off, 64);
    }
    s = __shfl(s, 0, 64);
    sq = __shfl(sq, 0, 64);
    float mean = s * (1.0f / DD);
    float var = sq * (1.0f / DD) - mean * mean;
    float rstd = rsqrtf(var + 1e-5f);
    float2 o;
    o.x = (v.x - mean) * rstd * g0 + b0;
    o.y = (v.y - mean) * rstd * g1 + b1;
    ((float2*)yp)[lane] = o;
}

__global__ __launch_bounds__(256) void ln_kernel(
    const float* __restrict__ x, const float* __restrict__ g,
    const float* __restrict__ b, float* __restrict__ y)
{
    int wave = threadIdx.x >> 6;
    int lane = threadIdx.x & 63;
    int row = blockIdx.x * 4 + wave;
    float2 v = ((const float2*)(x + (size_t)row * DD))[lane];
    float2 gg = ((const float2*)g)[lane];
    float2 bb = ((const float2*)b)[lane];
    ln_row(v, gg.x, gg.y, bb.x, bb.y, y + (size_t)row * DD, lane);
}

__global__ __launch_bounds__(256) void avgln_kernel(
    const float* __restrict__ xa, const float* __restrict__ xb,
    const float* __restrict__ g, const float* __restrict__ b, float* __restrict__ y)
{
    int wave = threadIdx.x >> 6;
    int lane = threadIdx.x & 63;
    int row = blockIdx.x * 4 + wave;
    float2 va = ((const float2*)(xa + (size_t)row * DD))[lane];
    float2 vb = ((const float2*)(xb + (size_t)row * DD))[lane];
    float2 v = make_float2((va.x + vb.x) * 0.5f, (va.y + vb.y) * 0.5f);
    float2 gg = ((const float2*)g)[lane];
    float2 bb = ((const float2*)b)[lane];
    ln_row(v, gg.x, gg.y, bb.x, bb.y, y + (size_t)row * DD, lane);
}

// ---------------- tiled fp32 GEMM: C = op(A[M,K] @ W[K,N] (+bias) (+res)) ----------------
// BM=128 BN=64 BK=32, 256 threads, 8x4 micro-tile
__device__ __forceinline__ float gelu_exact(float x) {
    return 0.5f * x * (1.0f + erff(x * 0.70710678118654752f));
}

template<int K, int N, bool BIAS, bool RES, bool GELU>
__global__ __launch_bounds__(256) void gemm_kernel(
    const float* __restrict__ A, const float* __restrict__ W,
    const float* __restrict__ bias, const float* __restrict__ Rsrc,
    float* __restrict__ Cdst)
{
    __shared__ float As[32][132];   // transposed A tile, +4 pad (16B-aligned rows)
    __shared__ float Bs[32][64];
    int tid = threadIdx.x;
    int tx = tid & 15;
    int ty = tid >> 4;
    int m0 = blockIdx.y * 128;
    int n0 = blockIdx.x * 64;
    float acc[8][4];
    #pragma unroll
    for (int i = 0; i < 8; ++i)
        #pragma unroll
        for (int j = 0; j < 4; ++j) acc[i][j] = 0.0f;

    for (int kt = 0; kt < K; kt += 32) {
        #pragma unroll
        for (int p = 0; p < 4; ++p) {
            int id = tid + p * 256;
            int r = id >> 3;
            int c = (id & 7) << 2;
            float4 av = *(const float4*)(A + (size_t)(m0 + r) * K + kt + c);
            As[c + 0][r] = av.x;
            As[c + 1][r] = av.y;
            As[c + 2][r] = av.z;
            As[c + 3][r] = av.w;
        }
        #pragma unroll
        for (int p = 0; p < 2; ++p) {
            int id = tid + p * 256;
            int r = id >> 4;
            int c = (id & 15) << 2;
            *(float4*)&Bs[r][c] = *(const float4*)(W + (size_t)(kt + r) * N + n0 + c);
        }
        __syncthreads();
        #pragma unroll
        for (int k = 0; k < 32; ++k) {
            float a[8], bb[4];
            *(float4*)&a[0] = *(float4*)&As[k][ty * 8];
            *(float4*)&a[4] = *(float4*)&As[k][ty * 8 + 4];
            *(float4*)&bb[0] = *(float4*)&Bs[k][tx * 4];
            #pragma unroll
            for (int i = 0; i < 8; ++i)
                #pragma unroll
                for (int j = 0; j < 4; ++j)
                    acc[i][j] = fmaf(a[i], bb[j], acc[i][j]);
        }
        __syncthreads();
    }

    float4 bv = make_float4(0.f, 0.f, 0.f, 0.f);
    if (BIAS) bv = *(const float4*)(bias + n0 + tx * 4);
    #pragma unroll
    for (int i = 0; i < 8; ++i) {
        int row = m0 + ty * 8 + i;
        int col = n0 + tx * 4;
        float4 r;
        r.x = acc[i][0] + bv.x;
        r.y = acc[i][1] + bv.y;
        r.z = acc[i][2] + bv.z;
        r.w = acc[i][3] + bv.w;
        if (GELU) {
            r.x = gelu_exact(r.x); r.y = gelu_exact(r.y);
            r.z = gelu_exact(r.z); r.w = gelu_exact(r.w);
        }
        if (RES) {
            float4 rr = *(const float4*)(Rsrc + (size_t)row * N + col);
            r.x += rr.x; r.y += rr.y; r.z += rr.z; r.w += rr.w;
        }
        *(float4*)(Cdst + (size_t)row * N + col) = r;
    }
}

// ---------------- attention: shared-QK, causal, self=-5e4 ----------------
__global__ __launch_bounds__(384) void attn_kernel(
    const float* __restrict__ qk, const float* __restrict__ v,
    float* __restrict__ o)
{
    int bh = blockIdx.x;
    int b = bh / HH, hh = bh % HH;
    const float* qkb = qk + (size_t)b * LL * DD + hh * DHH;
    const float* vb  = v  + (size_t)b * LL * DD + hh * DHH;
    __shared__ float kn[LL][DHH];
    __shared__ float vs[LL][DHH];
    int i = threadIdx.x;   // query row 0..383

    float q[DHH], vi[DHH];
    #pragma unroll
    for (int c = 0; c < 4; ++c) {
        float4 t = *(const float4*)(qkb + (size_t)i * DD + c * 4);
        q[c*4+0] = t.x; q[c*4+1] = t.y; q[c*4+2] = t.z; q[c*4+3] = t.w;
        float4 tv = *(const float4*)(vb + (size_t)i * DD + c * 4);
        vi[c*4+0] = tv.x; vi[c*4+1] = tv.y; vi[c*4+2] = tv.z; vi[c*4+3] = tv.w;
    }
    float nrm = 0.f;
    #pragma unroll
    for (int d = 0; d < DHH; ++d) nrm = fmaf(q[d], q[d], nrm);
    float inv = 1.0f / fmaxf(sqrtf(nrm), 1e-12f);
    #pragma unroll
    for (int d = 0; d < DHH; ++d) kn[i][d] = q[d] * inv;
    #pragma unroll
    for (int d = 0; d < DHH; ++d) vs[i][d] = vi[d];
    __syncthreads();

    // online softmax; self term (value -5e4) folded into init
    float m = -5.0e4f, l = 1.0f;
    float acc[DHH];
    #pragma unroll
    for (int d = 0; d < DHH; ++d) acc[d] = vi[d];

    for (int j = 0; j < i; ++j) {
        float kj[DHH], vj[DHH];
        #pragma unroll
        for (int c = 0; c < 4; ++c) {
            float4 t = *(const float4*)&kn[j][c * 4];
            kj[c*4+0] = t.x; kj[c*4+1] = t.y; kj[c*4+2] = t.z; kj[c*4+3] = t.w;
            float4 tv = *(const float4*)&vs[j][c * 4];
            vj[c*4+0] = tv.x; vj[c*4+1] = tv.y; vj[c*4+2] = tv.z; vj[c*4+3] = tv.w;
        }
        float s = 0.f;
        #pragma unroll
        for (int d = 0; d < DHH; ++d) s = fmaf(q[d], kj[d], s);
        s *= 0.25f;   // DH^-0.5
        if (s <= m) {
            float p = __expf(s - m);
            l += p;
            #pragma unroll
            for (int d = 0; d < DHH; ++d) acc[d] = fmaf(p, vj[d], acc[d]);
        } else {
            float c = __expf(m - s);
            l = l * c + 1.0f;
            #pragma unroll
            for (int d = 0; d < DHH; ++d) acc[d] = fmaf(acc[d], c, vj[d]);
            m = s;
        }
    }
    float inv_l = 1.0f / l;
    float* op = o + (size_t)(b * LL + i) * DD + hh * DHH;
    #pragma unroll
    for (int c = 0; c < 4; ++c) {
        float4 t;
        t.x = acc[c*4+0] * inv_l; t.y = acc[c*4+1] * inv_l;
        t.z = acc[c*4+2] * inv_l; t.w = acc[c*4+3] * inv_l;
        *(float4*)(op + c * 4) = t;
    }
}

// ---------------- final projection [64,49152] x [49152,128] ----------------
__global__ __launch_bounds__(256) void out_init_kernel(
    const float* __restrict__ bp, float* __restrict__ out)
{
    int t = blockIdx.x * 256 + threadIdx.x;   // 8192
    out[t] = bp[t & (COUT - 1)];
}

__global__ __launch_bounds__(256) void final_gemm_kernel(
    const float* __restrict__ xm, const float* __restrict__ Wp,
    float* __restrict__ out)
{
    int mt = blockIdx.x;        // 0..3 -> rows mt*16..+15
    int kc = blockIdx.y;        // 0..95 -> k chunk of 512
    int n = threadIdx.x & (COUT - 1);
    int mg = threadIdx.x >> 7;  // 0..1
    __shared__ float xs[16][64];
    float acc[8];
    #pragma unroll
    for (int i = 0; i < 8; ++i) acc[i] = 0.f;

    for (int ks = 0; ks < 512; ks += 64) {
        int k0 = kc * 512 + ks;
        int r = threadIdx.x >> 4;
        int cg = (threadIdx.x & 15) * 4;
        *(float4*)&xs[r][cg] = *(const float4*)(xm + (size_t)(mt * 16 + r) * KP + k0 + cg);
        __syncthreads();
        for (int k = 0; k < 64; ++k) {
            float w = Wp[(size_t)(k0 + k) * COUT + n];
            #pragma unroll
            for (int i = 0; i < 8; ++i)
                acc[i] = fmaf(xs[mg * 8 + i][k], w, acc[i]);
        }
        __syncthreads();
    }
    #pragma unroll
    for (int i = 0; i < 8; ++i)
        atomicAdd(&out[(mt * 16 + mg * 8 + i) * COUT + n], acc[i]);
}

// ---------------- launch ----------------
extern "C" void kernel_launch(void* const* d_in, const int* in_sizes, int n_in,
                              void* d_out, int out_size, void* d_ws, size_t ws_size,
                              hipStream_t stream)
{
    const int*   x_enc = (const int*)  d_in[0];
    const float* emb   = (const float*)d_in[1];
    const float* pos1  = (const float*)d_in[2];
    const float* pos2  = (const float*)d_in[3];
    const float* ln1_g = (const float*)d_in[4];
    const float* ln1_b = (const float*)d_in[5];
    const float* Wqk   = (const float*)d_in[6];
    const float* Wv    = (const float*)d_in[7];
    const float* Wo    = (const float*)d_in[8];
    const float* bo    = (const float*)d_in[9];
    const float* ln2_g = (const float*)d_in[10];
    const float* ln2_b = (const float*)d_in[11];
    const float* W1    = (const float*)d_in[12];
    const float* b1    = (const float*)d_in[13];
    const float* W2    = (const float*)d_in[14];
    const float* b2    = (const float*)d_in[15];
    const float* lnf_g = (const float*)d_in[16];
    const float* lnf_b = (const float*)d_in[17];
    const float* Wp    = (const float*)d_in[18];
    const float* bp    = (const float*)d_in[19];
    float* out = (float*)d_out;

    // workspace layout (floats); total 22,020,096 floats = 88 MB
    float* ws = (float*)d_ws;
    const size_t SZ = (size_t)MROWS * DD;          // 3,145,728
    float* x1  = ws;
    float* x2  = ws + SZ;
    float* h   = ws + 2 * SZ;
    float* buf = ws + 3 * SZ;                      // 4*SZ floats
    float* qk  = buf;
    float* v   = buf + SZ;
    float* o   = buf + 2 * SZ;
    float* hff = buf;                              // overlays qk/v/o (dead by then)

    embed_kernel<<<dim3(MROWS * 32 / 256), dim3(256), 0, stream>>>(x_enc, emb, pos1, pos2, x1, x2);

    for (int d = 0; d < DEPTH; ++d) {
        const float* l1g = ln1_g + d * DD;
        const float* l1b = ln1_b + d * DD;
        const float* wqk = Wqk + (size_t)d * DD * DD;
        const float* wv  = Wv  + (size_t)d * DD * DD;
        const float* wo  = Wo  + (size_t)d * DD * DD;
        const float* bod = bo  + d * DD;
        const float* l2g = ln2_g + d * DD;
        const float* l2b = ln2_b + d * DD;
        const float* w1  = W1 + (size_t)d * DD * FFD;
        const float* b1d = b1 + d * FFD;
        const float* w2  = W2 + (size_t)d * FFD * DD;
        const float* b2d = b2 + d * DD;

        ln_kernel<<<dim3(MROWS / 4), dim3(256), 0, stream>>>(x2, l1g, l1b, h);
        gemm_kernel<128, 128, false, false, false><<<dim3(2, 192), dim3(256), 0, stream>>>(h, wqk, nullptr, nullptr, qk);
        gemm_kernel<128, 128, false, false, false><<<dim3(2, 192), dim3(256), 0, stream>>>(h, wv, nullptr, nullptr, v);
        attn_kernel<<<dim3(BB * HH), dim3(LL), 0, stream>>>(qk, v, o);
        gemm_kernel<128, 128, true, true, false><<<dim3(2, 192), dim3(256), 0, stream>>>(o, wo, bod, x1, x1);
        ln_kernel<<<dim3(MROWS / 4), dim3(256), 0, stream>>>(x1, l2g, l2b, h);
        gemm_kernel<128, 512, true, false, true><<<dim3(8, 192), dim3(256), 0, stream>>>(h, w1, b1d, nullptr, hff);
        gemm_kernel<512, 128, true, true, false><<<dim3(2, 192), dim3(256), 0, stream>>>(hff, w2, b2d, x2, x2);
    }

    avgln_kernel<<<dim3(MROWS / 4), dim3(256), 0, stream>>>(x1, x2, lnf_g, lnf_b, h);
    out_init_kernel<<<dim3(32), dim3(256), 0, stream>>>(bp, out);
    final_gemm_kernel<<<dim3(4, 96), dim3(256), 0, stream>>>(h, Wp, out);
}

// Round 2
// 919.898 us; speedup vs baseline: 1.9774x; 1.9774x over previous
//
#include <hip/hip_runtime.h>
#include <hip/hip_bf16.h>
#include <math.h>

#define BB 64
#define LL 384
#define DD 128
#define HH 8
#define DHH 16
#define DEPTH 6
#define FFD 512
#define MROWS (BB*LL)      // 24576
#define COUT 128
#define KP (LL*DD)         // 49152

typedef short bf16x8 __attribute__((ext_vector_type(8)));
typedef float f32x4 __attribute__((ext_vector_type(4)));

// ---------------- embed + axial pos ----------------
__global__ __launch_bounds__(256) void embed_kernel(
    const int* __restrict__ x_enc, const float* __restrict__ emb,
    const float* __restrict__ pos1, const float* __restrict__ pos2,
    float* __restrict__ x1, float* __restrict__ x2)
{
    int t = blockIdx.x * 256 + threadIdx.x;      // over MROWS * 32 float4
    int row = t >> 5;
    int c4 = t & 31;
    int l = row % LL;
    int tok = x_enc[row];
    float4 a = ((const float4*)(emb + (size_t)tok * DD))[c4];
    float4 b = ((const float4*)(pos1 + (l / 25) * DD))[c4];
    float4 c = ((const float4*)(pos2 + (l % 25) * DD))[c4];
    float4 r = make_float4(a.x + b.x + c.x, a.y + b.y + c.y,
                           a.z + b.z + c.z, a.w + b.w + c.w);
    ((float4*)x1)[t] = r;
    ((float4*)x2)[t] = r;
}

// ---------------- weight cast + transpose: W[K,N] fp32 -> Wt[N,K] bf16 ----------------
__global__ __launch_bounds__(256) void castT_kernel(
    const float* __restrict__ src, __hip_bfloat16* __restrict__ dst, int K, int N)
{
    __shared__ float tile[32][33];
    int kb = blockIdx.x * 32, nb = blockIdx.y * 32;
    int tx = threadIdx.x & 31, ty = threadIdx.x >> 5;   // ty 0..7
    const float* s = src + (size_t)blockIdx.z * K * N;
    __hip_bfloat16* d = dst + (size_t)blockIdx.z * K * N;
    #pragma unroll
    for (int r = 0; r < 32; r += 8)
        tile[r + ty][tx] = s[(size_t)(kb + r + ty) * N + nb + tx];
    __syncthreads();
    #pragma unroll
    for (int r = 0; r < 32; r += 8)
        d[(size_t)(nb + r + ty) * K + kb + tx] = __float2bfloat16(tile[tx][r + ty]);
}

// ---------------- LayerNorm (wave per row) -> bf16 out ----------------
__global__ __launch_bounds__(256) void ln_kernel(
    const float* __restrict__ x, const float* __restrict__ g,
    const float* __restrict__ b, __hip_bfloat16* __restrict__ y)
{
    int wave = threadIdx.x >> 6;
    int lane = threadIdx.x & 63;
    int row = blockIdx.x * 4 + wave;
    float2 v = ((const float2*)(x + (size_t)row * DD))[lane];
    float2 gg = ((const float2*)g)[lane];
    float2 bb = ((const float2*)b)[lane];
    float s = v.x + v.y;
    float sq = v.x * v.x + v.y * v.y;
    #pragma unroll
    for (int off = 32; off > 0; off >>= 1) {
        s += __shfl_down(s, off, 64);
        sq += __shfl_down(sq, off, 64);
    }
    s = __shfl(s, 0, 64);
    sq = __shfl(sq, 0, 64);
    float mean = s * (1.0f / DD);
    float var = sq * (1.0f / DD) - mean * mean;
    float rstd = rsqrtf(var + 1e-5f);
    __hip_bfloat16* yp = y + (size_t)row * DD + lane * 2;
    yp[0] = __float2bfloat16((v.x - mean) * rstd * gg.x + bb.x);
    yp[1] = __float2bfloat16((v.y - mean) * rstd * gg.y + bb.y);
}

// avg + LN -> fp32 out (for final projection)
__global__ __launch_bounds__(256) void avgln_kernel(
    const float* __restrict__ xa, const float* __restrict__ xb,
    const float* __restrict__ g, const float* __restrict__ b, float* __restrict__ y)
{
    int wave = threadIdx.x >> 6;
    int lane = threadIdx.x & 63;
    int row = blockIdx.x * 4 + wave;
    float2 va = ((const float2*)(xa + (size_t)row * DD))[lane];
    float2 vb = ((const float2*)(xb + (size_t)row * DD))[lane];
    float2 v = make_float2((va.x + vb.x) * 0.5f, (va.y + vb.y) * 0.5f);
    float2 gg = ((const float2*)g)[lane];
    float2 bb = ((const float2*)b)[lane];
    float s = v.x + v.y;
    float sq = v.x * v.x + v.y * v.y;
    #pragma unroll
    for (int off = 32; off > 0; off >>= 1) {
        s += __shfl_down(s, off, 64);
        sq += __shfl_down(sq, off, 64);
    }
    s = __shfl(s, 0, 64);
    sq = __shfl(sq, 0, 64);
    float mean = s * (1.0f / DD);
    float var = sq * (1.0f / DD) - mean * mean;
    float rstd = rsqrtf(var + 1e-5f);
    float2 o;
    o.x = (v.x - mean) * rstd * gg.x + bb.x;
    o.y = (v.y - mean) * rstd * gg.y + bb.y;
    ((float2*)(y + (size_t)row * DD))[lane] = o;
}

// ---------------- bf16 MFMA GEMM ----------------
// A[M,K] bf16 row-major, Bt[N,K] bf16 row-major (i.e. W transposed)
// C[row,col] = sum_k A[row,k]*Bt[col,k]  (+bias)(+res)(gelu)
// Block: 256 thr = 4 waves (2x2), BM=64, BN=128, K-tile=128
// LDS swizzle: 16B chunk c of row r stored at chunk slot r*16 + (c ^ (r&7))
__device__ __forceinline__ float gelu_exact(float x) {
    return 0.5f * x * (1.0f + erff(x * 0.70710678118654752f));
}

template<int K, int N, bool BIAS, bool RES, bool GELU, bool OBF>
__global__ __launch_bounds__(256) void gemm_bf16(
    const __hip_bfloat16* __restrict__ A, const __hip_bfloat16* __restrict__ Bt,
    const float* __restrict__ bias, const float* __restrict__ Rsrc,
    void* __restrict__ Cdst)
{
    __shared__ unsigned short As[64 * 128];    // 16 KB
    __shared__ unsigned short Bs[128 * 128];   // 32 KB
    int tid = threadIdx.x;
    int l = tid & 63, w = tid >> 6;
    int wr = w >> 1, wc = w & 1;
    int lr = l & 15, q = l >> 4;
    int m0 = blockIdx.y * 64;
    int n0 = blockIdx.x * 128;

    f32x4 acc[2][4];
    #pragma unroll
    for (int mt = 0; mt < 2; ++mt)
        #pragma unroll
        for (int nt = 0; nt < 4; ++nt) acc[mt][nt] = (f32x4){0.f, 0.f, 0.f, 0.f};

    for (int kt = 0; kt < K; kt += 128) {
        if (kt) __syncthreads();
        // stage A: 1024 chunks of 16B
        #pragma unroll
        for (int p = 0; p < 4; ++p) {
            int n = p * 256 + tid;
            int r = n >> 4;
            int c = (n & 15) ^ (r & 7);
            uint4 dv = *(const uint4*)(A + (size_t)(m0 + r) * K + kt + c * 8);
            *(uint4*)&As[n * 8] = dv;
        }
        // stage B: 2048 chunks
        #pragma unroll
        for (int p = 0; p < 8; ++p) {
            int n = p * 256 + tid;
            int r = n >> 4;
            int c = (n & 15) ^ (r & 7);
            uint4 dv = *(const uint4*)(Bt + (size_t)(n0 + r) * K + kt + c * 8);
            *(uint4*)&Bs[n * 8] = dv;
        }
        __syncthreads();

        #pragma unroll
        for (int kk = 0; kk < 4; ++kk) {
            bf16x8 afr[2], bfr[4];
            #pragma unroll
            for (int mt = 0; mt < 2; ++mt) {
                int rA = wr * 32 + mt * 16 + lr;
                int cc = (kk * 4 + q) ^ (rA & 7);
                afr[mt] = *(const bf16x8*)&As[(rA * 16 + cc) * 8];
            }
            #pragma unroll
            for (int nt = 0; nt < 4; ++nt) {
                int rB = wc * 64 + nt * 16 + lr;
                int cc = (kk * 4 + q) ^ (rB & 7);
                bfr[nt] = *(const bf16x8*)&Bs[(rB * 16 + cc) * 8];
            }
            #pragma unroll
            for (int mt = 0; mt < 2; ++mt)
                #pragma unroll
                for (int nt = 0; nt < 4; ++nt)
                    acc[mt][nt] = __builtin_amdgcn_mfma_f32_16x16x32_bf16(
                        afr[mt], bfr[nt], acc[mt][nt], 0, 0, 0);
        }
    }

    // epilogue: C layout col=lane&15, row=(lane>>4)*4+reg
    #pragma unroll
    for (int mt = 0; mt < 2; ++mt) {
        #pragma unroll
        for (int nt = 0; nt < 4; ++nt) {
            int col = n0 + wc * 64 + nt * 16 + lr;
            float bv = BIAS ? bias[col] : 0.f;
            #pragma unroll
            for (int r = 0; r < 4; ++r) {
                int row = m0 + wr * 32 + mt * 16 + q * 4 + r;
                float val = acc[mt][nt][r] + bv;
                if (GELU) val = gelu_exact(val);
                if (RES) val += Rsrc[(size_t)row * N + col];
                if (OBF) ((__hip_bfloat16*)Cdst)[(size_t)row * N + col] = __float2bfloat16(val);
                else     ((float*)Cdst)[(size_t)row * N + col] = val;
            }
        }
    }
}

// ---------------- attention: shared-QK, causal, fixed-max softmax ----------------
// s_j = (q . khat_j)/4 <= |q|/4 = mfix  (Cauchy-Schwarz), so p = exp(s - mfix) in [e^-0.5,1].
// Self term exp(-5e4 - m) == 0 in fp32 (as in reference); i==0 -> o = v_i.
__global__ __launch_bounds__(384) void attn_kernel(
    const float* __restrict__ qk, const float* __restrict__ v,
    __hip_bfloat16* __restrict__ o)
{
    int bh = blockIdx.x;
    int b = bh >> 3, hh = bh & 7;
    const float* qkb = qk + (size_t)b * LL * DD + hh * DHH;
    const float* vb  = v  + (size_t)b * LL * DD + hh * DHH;
    __shared__ float kn[LL][DHH];
    __shared__ float vs[LL][DHH];
    int i = threadIdx.x;   // query row 0..383

    float qv[DHH], vi[DHH];
    #pragma unroll
    for (int c = 0; c < 4; ++c) {
        float4 t = *(const float4*)(qkb + (size_t)i * DD + c * 4);
        qv[c*4+0] = t.x; qv[c*4+1] = t.y; qv[c*4+2] = t.z; qv[c*4+3] = t.w;
        float4 tv = *(const float4*)(vb + (size_t)i * DD + c * 4);
        vi[c*4+0] = tv.x; vi[c*4+1] = tv.y; vi[c*4+2] = tv.z; vi[c*4+3] = tv.w;
    }
    float nrm = 0.f;
    #pragma unroll
    for (int d = 0; d < DHH; ++d) nrm = fmaf(qv[d], qv[d], nrm);
    float qn = sqrtf(nrm);
    float inv = 1.0f / fmaxf(qn, 1e-12f);
    float mfix = 0.25f * qn;
    #pragma unroll
    for (int c = 0; c < 4; ++c) {
        float4 t;
        t.x = qv[c*4+0]*inv; t.y = qv[c*4+1]*inv; t.z = qv[c*4+2]*inv; t.w = qv[c*4+3]*inv;
        *(float4*)&kn[i][c*4] = t;
        *(float4*)&vs[i][c*4] = *(const float4*)&vi[c*4];
    }
    __syncthreads();

    float l = 0.f;
    float acc[DHH];
    #pragma unroll
    for (int d = 0; d < DHH; ++d) acc[d] = 0.f;

    int j = 0;
    for (; j + 2 <= i; j += 2) {
        float k0[DHH], k1[DHH], v0[DHH], v1[DHH];
        #pragma unroll
        for (int c = 0; c < 4; ++c) {
            *(float4*)&k0[c*4] = *(const float4*)&kn[j][c*4];
            *(float4*)&k1[c*4] = *(const float4*)&kn[j+1][c*4];
            *(float4*)&v0[c*4] = *(const float4*)&vs[j][c*4];
            *(float4*)&v1[c*4] = *(const float4*)&vs[j+1][c*4];
        }
        float s0 = 0.f, s1 = 0.f;
        #pragma unroll
        for (int d = 0; d < DHH; ++d) {
            s0 = fmaf(qv[d], k0[d], s0);
            s1 = fmaf(qv[d], k1[d], s1);
        }
        float p0 = __expf(fmaf(s0, 0.25f, -mfix));
        float p1 = __expf(fmaf(s1, 0.25f, -mfix));
        l += p0 + p1;
        #pragma unroll
        for (int d = 0; d < DHH; ++d)
            acc[d] = fmaf(p1, v1[d], fmaf(p0, v0[d], acc[d]));
    }
    if (j < i) {
        float k0[DHH], v0[DHH];
        #pragma unroll
        for (int c = 0; c < 4; ++c) {
            *(float4*)&k0[c*4] = *(const float4*)&kn[j][c*4];
            *(float4*)&v0[c*4] = *(const float4*)&vs[j][c*4];
        }
        float s0 = 0.f;
        #pragma unroll
        for (int d = 0; d < DHH; ++d) s0 = fmaf(qv[d], k0[d], s0);
        float p0 = __expf(fmaf(s0, 0.25f, -mfix));
        l += p0;
        #pragma unroll
        for (int d = 0; d < DHH; ++d) acc[d] = fmaf(p0, v0[d], acc[d]);
    }

    if (i == 0) {
        l = 1.0f;
        #pragma unroll
        for (int d = 0; d < DHH; ++d) acc[d] = vi[d];
    }
    float invl = 1.0f / l;
    __hip_bfloat16 tmp[DHH];
    #pragma unroll
    for (int d = 0; d < DHH; ++d) tmp[d] = __float2bfloat16(acc[d] * invl);
    uint4* op = (uint4*)(o + (size_t)(b * LL + i) * DD + hh * DHH);
    op[0] = *(uint4*)&tmp[0];
    op[1] = *(uint4*)&tmp[8];
}

// ---------------- final projection [64,49152] x [49152,128] ----------------
__global__ __launch_bounds__(256) void out_init_kernel(
    const float* __restrict__ bp, float* __restrict__ out)
{
    int t = blockIdx.x * 256 + threadIdx.x;   // 8192
    out[t] = bp[t & (COUT - 1)];
}

__global__ __launch_bounds__(256) void final_gemm_kernel(
    const float* __restrict__ xm, const float* __restrict__ Wp,
    float* __restrict__ out)
{
    int mt = blockIdx.x;        // 0..3 -> rows mt*16..+15
    int kc = blockIdx.y;        // 0..95 -> k chunk of 512
    int n = threadIdx.x & (COUT - 1);
    int mg = threadIdx.x >> 7;  // 0..1
    __shared__ float xs[16][64];
    float acc[8];
    #pragma unroll
    for (int i = 0; i < 8; ++i) acc[i] = 0.f;

    for (int ks = 0; ks < 512; ks += 64) {
        int k0 = kc * 512 + ks;
        int r = threadIdx.x >> 4;
        int cg = (threadIdx.x & 15) * 4;
        *(float4*)&xs[r][cg] = *(const float4*)(xm + (size_t)(mt * 16 + r) * KP + k0 + cg);
        __syncthreads();
        for (int k = 0; k < 64; ++k) {
            float wv = Wp[(size_t)(k0 + k) * COUT + n];
            #pragma unroll
            for (int i = 0; i < 8; ++i)
                acc[i] = fmaf(xs[mg * 8 + i][k], wv, acc[i]);
        }
        __syncthreads();
    }
    #pragma unroll
    for (int i = 0; i < 8; ++i)
        atomicAdd(&out[(mt * 16 + mg * 8 + i) * COUT + n], acc[i]);
}

// ---------------- launch ----------------
extern "C" void kernel_launch(void* const* d_in, const int* in_sizes, int n_in,
                              void* d_out, int out_size, void* d_ws, size_t ws_size,
                              hipStream_t stream)
{
    const int*   x_enc = (const int*)  d_in[0];
    const float* emb   = (const float*)d_in[1];
    const float* pos1  = (const float*)d_in[2];
    const float* pos2  = (const float*)d_in[3];
    const float* ln1_g = (const float*)d_in[4];
    const float* ln1_b = (const float*)d_in[5];
    const float* Wqk   = (const float*)d_in[6];
    const float* Wv    = (const float*)d_in[7];
    const float* Wo    = (const float*)d_in[8];
    const float* bo    = (const float*)d_in[9];
    const float* ln2_g = (const float*)d_in[10];
    const float* ln2_b = (const float*)d_in[11];
    const float* W1    = (const float*)d_in[12];
    const float* b1    = (const float*)d_in[13];
    const float* W2    = (const float*)d_in[14];
    const float* b2    = (const float*)d_in[15];
    const float* lnf_g = (const float*)d_in[16];
    const float* lnf_b = (const float*)d_in[17];
    const float* Wp    = (const float*)d_in[18];
    const float* bp    = (const float*)d_in[19];
    float* out = (float*)d_out;

    // workspace layout; SZ = 3,145,728 elements
    const size_t SZ = (size_t)MROWS * DD;
    float* ws_f = (float*)d_ws;
    float* x1 = ws_f;                    // fp32 [M,128]
    float* x2 = ws_f + SZ;               // fp32 [M,128]
    float* R  = ws_f + 2 * SZ;           // 2*SZ floats shared region
    float* qk = R;                       // fp32 [M,128]  (lifetime: ln1..attn)
    float* vv = R + SZ;                  // fp32 [M,128]
    __hip_bfloat16* hff = (__hip_bfloat16*)R;   // bf16 [M,512] (lifetime: ff1..ff2)
    float* hfin = R;                     // fp32 [M,128]  (final LN out)
    __hip_bfloat16* h_bf = (__hip_bfloat16*)(ws_f + 4 * SZ);  // bf16 [M,128]
    __hip_bfloat16* o_bf = h_bf + SZ;                          // bf16 [M,128]
    __hip_bfloat16* wT   = o_bf + SZ;    // transposed bf16 weights
    __hip_bfloat16* wqkT = wT;                       // 6 * 128*128
    __hip_bfloat16* wvT  = wqkT + 6 * 16384;
    __hip_bfloat16* woT  = wvT  + 6 * 16384;
    __hip_bfloat16* w1T  = woT  + 6 * 16384;         // 6 * 512*128
    __hip_bfloat16* w2T  = w1T  + 6 * 65536;         // 6 * 128*512

    // weight casts (transpose to [N,K] bf16)
    castT_kernel<<<dim3(4, 4, 6),  dim3(256), 0, stream>>>(Wqk, wqkT, 128, 128);
    castT_kernel<<<dim3(4, 4, 6),  dim3(256), 0, stream>>>(Wv,  wvT,  128, 128);
    castT_kernel<<<dim3(4, 4, 6),  dim3(256), 0, stream>>>(Wo,  woT,  128, 128);
    castT_kernel<<<dim3(4, 16, 6), dim3(256), 0, stream>>>(W1,  w1T,  128, 512);
    castT_kernel<<<dim3(16, 4, 6), dim3(256), 0, stream>>>(W2,  w2T,  512, 128);

    embed_kernel<<<dim3(MROWS * 32 / 256), dim3(256), 0, stream>>>(x_enc, emb, pos1, pos2, x1, x2);

    for (int d = 0; d < DEPTH; ++d) {
        const float* l1g = ln1_g + d * DD;
        const float* l1b = ln1_b + d * DD;
        const float* bod = bo + d * DD;
        const float* l2g = ln2_g + d * DD;
        const float* l2b = ln2_b + d * DD;
        const float* b1d = b1 + d * FFD;
        const float* b2d = b2 + d * DD;
        const __hip_bfloat16* wqk_d = wqkT + (size_t)d * 16384;
        const __hip_bfloat16* wv_d  = wvT  + (size_t)d * 16384;
        const __hip_bfloat16* wo_d  = woT  + (size_t)d * 16384;
        const __hip_bfloat16* w1_d  = w1T  + (size_t)d * 65536;
        const __hip_bfloat16* w2_d  = w2T  + (size_t)d * 65536;

        ln_kernel<<<dim3(MROWS / 4), dim3(256), 0, stream>>>(x2, l1g, l1b, h_bf);
        gemm_bf16<128, 128, false, false, false, false>
            <<<dim3(1, MROWS / 64), dim3(256), 0, stream>>>(h_bf, wqk_d, nullptr, nullptr, qk);
        gemm_bf16<128, 128, false, false, false, false>
            <<<dim3(1, MROWS / 64), dim3(256), 0, stream>>>(h_bf, wv_d, nullptr, nullptr, vv);
        attn_kernel<<<dim3(BB * HH), dim3(LL), 0, stream>>>(qk, vv, o_bf);
        gemm_bf16<128, 128, true, true, false, false>
            <<<dim3(1, MROWS / 64), dim3(256), 0, stream>>>(o_bf, wo_d, bod, x1, x1);
        ln_kernel<<<dim3(MROWS / 4), dim3(256), 0, stream>>>(x1, l2g, l2b, h_bf);
        gemm_bf16<128, 512, true, false, true, true>
            <<<dim3(4, MROWS / 64), dim3(256), 0, stream>>>(h_bf, w1_d, b1d, nullptr, hff);
        gemm_bf16<512, 128, true, true, false, false>
            <<<dim3(1, MROWS / 64), dim3(256), 0, stream>>>(hff, w2_d, b2d, x2, x2);
    }

    avgln_kernel<<<dim3(MROWS / 4), dim3(256), 0, stream>>>(x1, x2, lnf_g, lnf_b, hfin);
    out_init_kernel<<<dim3(32), dim3(256), 0, stream>>>(bp, out);
    final_gemm_kernel<<<dim3(4, 96), dim3(256), 0, stream>>>(hfin, Wp, out);
}